// Round 2
// baseline (160.004 us; speedup 1.0000x reference)
//
#include <hip/hip_runtime.h>
#include <math.h>

#define N_POINTS 16384
#define N_CLOUDS 8
#define GRID_DIM 16                 // 16^3 cells per cloud; cell size = r = 1/16
#define CELLS_PER_CLOUD 4096
#define N_CELLS (N_CLOUDS * CELLS_PER_CLOUD)
#define NBR_STRIDE 32               // E[cnt]~2.1 (Poisson): P(cnt>32) ~ 1e-25

constexpr double R2D = 1.0 / 256.0;   // (1/16)^2, exact in binary

// ---------------------------------------------------------------------------
// K1: pos copy + batch->float copy + per-point cell id + cell histogram
// grid 64 x 256 == N_POINTS threads
// ---------------------------------------------------------------------------
__global__ __launch_bounds__(256) void k_prep(const float* __restrict__ pos,
                                              const int* __restrict__ batch,
                                              float* __restrict__ out,
                                              int* __restrict__ cell_of,
                                              int* __restrict__ counts)
{
    int i = blockIdx.x * 256 + threadIdx.x;
    // output 0: pos copy [N,3]
    for (int k = i; k < 3 * N_POINTS; k += N_POINTS) out[k] = pos[k];
    // output 2: batch as float (after pos 3N and out 32N)
    out[3 * N_POINTS + 32 * N_POINTS + i] = (float)batch[i];

    float x = pos[3 * i], y = pos[3 * i + 1], z = pos[3 * i + 2];
    int ix = min(max((int)(x * 16.f), 0), 15);
    int iy = min(max((int)(y * 16.f), 0), 15);
    int iz = min(max((int)(z * 16.f), 0), 15);
    int cell = ((batch[i] * GRID_DIM + iz) * GRID_DIM + iy) * GRID_DIM + ix;
    cell_of[i] = cell;
    atomicAdd(&counts[cell], 1);
}

// ---------------------------------------------------------------------------
// K2: single-block exclusive prefix sum over 32768 cell counts.
// 256 threads x 128-element chunks. Also initializes the scatter cursor.
// ---------------------------------------------------------------------------
__global__ __launch_bounds__(256) void k_scan(const int* __restrict__ counts,
                                              int* __restrict__ offsets,
                                              int* __restrict__ cursor)
{
    __shared__ int part[256];
    int t = threadIdx.x;
    int base = t * 128;
    int s = 0;
    for (int k = 0; k < 128; k++) s += counts[base + k];
    part[t] = s;
    __syncthreads();
    // Hillis-Steele inclusive scan of 256 partials
    for (int off = 1; off < 256; off <<= 1) {
        int v = (t >= off) ? part[t - off] : 0;
        __syncthreads();
        part[t] += v;
        __syncthreads();
    }
    int running = part[t] - s;        // exclusive base for this chunk
    for (int k = 0; k < 128; k++) {
        offsets[base + k] = running;
        cursor[base + k]  = running;
        running += counts[base + k];
    }
    if (t == 255) offsets[N_CELLS] = part[255];   // == N_POINTS
}

// ---------------------------------------------------------------------------
// K3: counting-sort scatter: sorted point ids + cell-sorted positions
// ---------------------------------------------------------------------------
__global__ __launch_bounds__(256) void k_scatter(const float* __restrict__ pos,
                                                 const int* __restrict__ cell_of,
                                                 int* __restrict__ cursor,
                                                 int* __restrict__ sorted,
                                                 float* __restrict__ pos_s)
{
    int i = blockIdx.x * 256 + threadIdx.x;
    int slot = atomicAdd(&cursor[cell_of[i]], 1);
    sorted[slot] = i;
    pos_s[3 * slot]     = pos[3 * i];
    pos_s[3 * slot + 1] = pos[3 * i + 1];
    pos_s[3 * slot + 2] = pos[3 * i + 2];
}

// ---------------------------------------------------------------------------
// K4: cell-based radius search (fp64 test) fused with layer a (6->8->8).
// One THREAD per point; ~13.5 candidates, ~2.1 hits expected.
// ---------------------------------------------------------------------------
__global__ __launch_bounds__(256) void k_search_a(
    const float* __restrict__ pos, const int* __restrict__ cell_of,
    const int* __restrict__ offsets, const int* __restrict__ sorted,
    const float* __restrict__ pos_s,
    const float* __restrict__ W1, const float* __restrict__ b1,
    const float* __restrict__ W2, const float* __restrict__ b2,
    float* __restrict__ out_a, int* __restrict__ nbr_idx, int* __restrict__ nbr_cnt)
{
    __shared__ float sW1[48], sB1[8], sW2[64], sB2[8];
    int t = threadIdx.x;
    if      (t < 48)  sW1[t]       = W1[t];
    else if (t < 56)  sB1[t - 48]  = b1[t - 48];
    else if (t < 120) sW2[t - 56]  = W2[t - 56];
    else if (t < 128) sB2[t - 120] = b2[t - 120];
    __syncthreads();

    int i = blockIdx.x * 256 + t;
    float xi = pos[3 * i], yi = pos[3 * i + 1], zi = pos[3 * i + 2];
    double xd = (double)xi, yd = (double)yi, zd = (double)zi;

    int cp  = cell_of[i];
    int zyx = cp & (CELLS_PER_CLOUD - 1);
    int cb  = cp - zyx;                      // cloud base
    int ix = zyx & 15, iy = (zyx >> 4) & 15, iz = (zyx >> 8) & 15;
    int x0 = max(ix - 1, 0), x1 = min(ix + 1, 15);
    int y0 = max(iy - 1, 0), y1 = min(iy + 1, 15);
    int z0 = max(iz - 1, 0), z1 = min(iz + 1, 15);

    float mx[8];
#pragma unroll
    for (int m = 0; m < 8; m++) mx[m] = 0.f;   // self always valid, relu >= 0
    int cnt = 0;

    for (int zz = z0; zz <= z1; zz++)
        for (int yy = y0; yy <= y1; yy++) {
            int b = cb + zz * 256 + yy * 16;
            int s = offsets[b + x0], e = offsets[b + x1 + 1];
            for (int u = s; u < e; u++) {
                float xj = pos_s[3 * u], yj = pos_s[3 * u + 1], zj = pos_s[3 * u + 2];
                double dx = xd - (double)xj, dy = yd - (double)yj, dz = zd - (double)zj;
                double d2 = dx * dx + dy * dy + dz * dz;
                if (d2 <= R2D) {
                    if (cnt < NBR_STRIDE) nbr_idx[i * NBR_STRIDE + cnt] = sorted[u];
                    cnt++;
                    float in6[6] = { xj, yj, zj, xj - xi, yj - yi, zj - zi };
#pragma unroll
                    for (int m = 0; m < 8; m++) {
                        float h = sB1[m];
#pragma unroll
                        for (int k = 0; k < 6; k++) h = fmaf(in6[k], sW1[k * 8 + m], h);
                        mx[m] = fmaxf(mx[m], fmaxf(h, 0.f));
                    }
                }
            }
        }

    nbr_cnt[i] = min(cnt, NBR_STRIDE);
#pragma unroll
    for (int m = 0; m < 8; m++) {
        float o = sB2[m];
#pragma unroll
        for (int k = 0; k < 8; k++) o = fmaf(mx[k], sW2[k * 8 + m], o);
        out_a[i * 8 + m] = o > 0.f ? o : expm1f(o);   // celu, alpha=1
    }
}

// ---------------------------------------------------------------------------
// K5/K6: PointNetConv over recorded neighbor lists.
// thread = (point p, channel m); CMID == COUT; PTS * CMID == 256.
// ---------------------------------------------------------------------------
template<int CIN, int CMID, int COUT, int PTS>
__global__ __launch_bounds__(256) void k_conv(
    const float* __restrict__ pos, const float* __restrict__ xin,
    const int* __restrict__ nbr_idx, const int* __restrict__ nbr_cnt,
    const float* __restrict__ W1, const float* __restrict__ b1,
    const float* __restrict__ W2, const float* __restrict__ b2,
    float* __restrict__ xout)
{
    __shared__ float s_agg[PTS][CMID];
    int p = threadIdx.x / CMID;
    int m = threadIdx.x % CMID;
    int i = blockIdx.x * PTS + p;

    float xi = pos[3 * i], yi = pos[3 * i + 1], zi = pos[3 * i + 2];
    int cnt = nbr_cnt[i];

    float w1c[CIN + 3];
#pragma unroll
    for (int k = 0; k < CIN + 3; k++) w1c[k] = W1[k * CMID + m];
    float bb = b1[m];

    float mx = 0.f;                                   // self always valid, relu >= 0
    for (int t = 0; t < cnt; t++) {
        int j = nbr_idx[i * NBR_STRIDE + t];
        float h = bb;
#pragma unroll
        for (int k = 0; k < CIN; k++) h = fmaf(xin[j * CIN + k], w1c[k], h);
        h = fmaf(pos[3 * j]     - xi, w1c[CIN + 0], h);
        h = fmaf(pos[3 * j + 1] - yi, w1c[CIN + 1], h);
        h = fmaf(pos[3 * j + 2] - zi, w1c[CIN + 2], h);
        mx = fmaxf(mx, fmaxf(h, 0.f));
    }
    s_agg[p][m] = mx;
    __syncthreads();

    float o = b2[m];
#pragma unroll
    for (int k = 0; k < CMID; k++) o = fmaf(s_agg[p][k], W2[k * COUT + m], o);
    xout[i * COUT + m] = o > 0.f ? o : expm1f(o);     // celu, alpha=1
}

// ---------------------------------------------------------------------------
extern "C" void kernel_launch(void* const* d_in, const int* in_sizes, int n_in,
                              void* d_out, int out_size, void* d_ws, size_t ws_size,
                              hipStream_t stream)
{
    const float* pos   = (const float*)d_in[0];
    // d_in[1] = rgb: unused by reference
    const int*   batch = (const int*)d_in[2];
    const float* W1a = (const float*)d_in[3];
    const float* b1a = (const float*)d_in[4];
    const float* W2a = (const float*)d_in[5];
    const float* b2a = (const float*)d_in[6];
    const float* W1b = (const float*)d_in[7];
    const float* b1b = (const float*)d_in[8];
    const float* W2b = (const float*)d_in[9];
    const float* b2b = (const float*)d_in[10];
    const float* W1c = (const float*)d_in[11];
    const float* b1c = (const float*)d_in[12];
    const float* W2c = (const float*)d_in[13];
    const float* b2c = (const float*)d_in[14];

    float* out = (float*)d_out;

    char* ws = (char*)d_ws;
    size_t off = 0;
    auto alloc = [&](size_t bytes) { char* p = ws + off; off += (bytes + 255) & ~size_t(255); return p; };
    int*   counts   = (int*)alloc(N_CELLS * 4);
    int*   offsets  = (int*)alloc((N_CELLS + 1) * 4);
    int*   cursor   = (int*)alloc(N_CELLS * 4);
    int*   cell_of  = (int*)alloc(N_POINTS * 4);
    int*   sorted   = (int*)alloc(N_POINTS * 4);
    float* pos_s    = (float*)alloc(N_POINTS * 3 * 4);
    int*   nbr_cnt  = (int*)alloc(N_POINTS * 4);
    int*   nbr_idx  = (int*)alloc(N_POINTS * NBR_STRIDE * 4);
    float* out_a    = (float*)alloc(N_POINTS * 8 * 4);
    float* out_b    = (float*)alloc(N_POINTS * 16 * 4);

    hipMemsetAsync(counts, 0, N_CELLS * 4, stream);
    hipLaunchKernelGGL(k_prep, dim3(N_POINTS / 256), dim3(256), 0, stream,
                       pos, batch, out, cell_of, counts);
    hipLaunchKernelGGL(k_scan, dim3(1), dim3(256), 0, stream,
                       counts, offsets, cursor);
    hipLaunchKernelGGL(k_scatter, dim3(N_POINTS / 256), dim3(256), 0, stream,
                       pos, cell_of, cursor, sorted, pos_s);
    hipLaunchKernelGGL(k_search_a, dim3(N_POINTS / 256), dim3(256), 0, stream,
                       pos, cell_of, offsets, sorted, pos_s,
                       W1a, b1a, W2a, b2a, out_a, nbr_idx, nbr_cnt);
    hipLaunchKernelGGL((k_conv<8, 16, 16, 16>), dim3(N_POINTS / 16), dim3(256), 0, stream,
                       pos, out_a, nbr_idx, nbr_cnt, W1b, b1b, W2b, b2b, out_b);
    hipLaunchKernelGGL((k_conv<16, 32, 32, 8>), dim3(N_POINTS / 8), dim3(256), 0, stream,
                       pos, out_b, nbr_idx, nbr_cnt, W1c, b1c, W2c, b2c,
                       out + 3 * N_POINTS);
}